// Round 5
// baseline (218.903 us; speedup 1.0000x reference)
//
#include <hip/hip_runtime.h>
#include <hip/hip_cooperative_groups.h>

namespace cg = cooperative_groups;

// DSBatchNorm fused: per-domain batch stats + affine. N=16384, F=1024, D=8.
// ONE cooperative kernel, grid=256 blocks x 256 threads (<=1 block/CU -> trivially
// co-resident), two grid.sync()s replace two kernel boundaries:
//   phase 1: block (rg,h) accumulates per-domain s1/s2 for 128 rows x half-row
//            in registers -> 8 MiB partials (RG=128; R2 proved 1-block/CU is
//            BW-saturating for this phase). Per-rowgroup y-histogram -> ws.
//   phase 2: 256 blocks x 32 (d,f)-pairs: coalesced 128->1 reduction along the
//            rowgroup axis, counts folded into scale/shift (edge cases:
//            count==1 -> (1,0) passthrough, count==0 -> (0,0)).
//   phase 3: out = x*scale[y] + shift[y], 64 rows/block, 8-row MLP unroll.

#define EPSV 1e-5f
constexpr int N = 16384;
constexpr int F = 1024;
constexpr int D = 8;
constexpr int RPB = 128;        // rows per rowgroup
constexpr int RG = N / RPB;     // 128 rowgroups
constexpr int GRID = RG * 2;    // 256 blocks (2 column halves)

__global__ __launch_bounds__(256) void ds_bn_fused(
    const float* __restrict__ x, const int* __restrict__ y,
    const float* __restrict__ gamma, const float* __restrict__ beta,
    float* __restrict__ out, float* __restrict__ partials,
    int* __restrict__ cnt_parts, float* __restrict__ scale,
    float* __restrict__ shift) {
  cg::grid_group gg = cg::this_grid();
  const int t = threadIdx.x;
  const int b = blockIdx.x;

  __shared__ int hist[D];
  __shared__ int sc[256];
  __shared__ float sf[8][32][2];

  // ---------------- phase 1: partial sums ----------------
  {
    const int rg = b >> 1;
    const int h = b & 1;

    if (t < D) hist[t] = 0;
    __syncthreads();
    if (h == 0 && t < RPB) atomicAdd(&hist[y[rg * RPB + t]], 1);
    __syncthreads();
    if (h == 0 && t < D) cnt_parts[rg * D + t] = hist[t];  // one writer per rg

    float2 a1[D], a2[D];
#pragma unroll
    for (int k = 0; k < D; ++k) {
      a1[k] = make_float2(0.f, 0.f);
      a2[k] = make_float2(0.f, 0.f);
    }

    const float2* __restrict__ x2 = (const float2*)x;
    const int col2 = h * 256 + t;  // float2 column, 0..511
    const int row0 = rg * RPB;

#define ACC(K)                            \
  a1[K].x += v.x;                         \
  a1[K].y += v.y;                         \
  a2[K].x = fmaf(v.x, v.x, a2[K].x);      \
  a2[K].y = fmaf(v.y, v.y, a2[K].y);      \
  break;

    for (int r = 0; r < RPB; r += 8) {
      const int n = row0 + r;
      int dd[8];
      float2 vv[8];
#pragma unroll
      for (int j = 0; j < 8; ++j) dd[j] = y[n + j];  // uniform -> SGPR
#pragma unroll
      for (int j = 0; j < 8; ++j) vv[j] = x2[(size_t)(n + j) * 512 + col2];
#pragma unroll
      for (int j = 0; j < 8; ++j) {
        float2 v = vv[j];
        switch (dd[j]) {
          case 0: ACC(0)
          case 1: ACC(1)
          case 2: ACC(2)
          case 3: ACC(3)
          case 4: ACC(4)
          case 5: ACC(5)
          case 6: ACC(6)
          case 7: ACC(7)
        }
      }
    }
#undef ACC

    // partials as float2: pp[(rg*D + d)*1024 + f] = (s1, s2)
    float4* __restrict__ p4 = (float4*)partials;
#pragma unroll
    for (int k = 0; k < D; ++k) {
      float4 w = make_float4(a1[k].x, a2[k].x, a1[k].y, a2[k].y);
      p4[(rg * D + k) * 512 + h * 256 + t] = w;
    }
  }

  gg.sync();

  // ---------------- phase 2: 128->1 reduction -> scale/shift ----------------
  {
    const int i = t & 31;   // pair within block
    const int ch = t >> 5;  // rowgroup chunk, 0..7 (16 rowgroups each)
    const int p = b * 32 + i;  // (d,f) flat, 0..8191
    const int d = p >> 10;     // uniform per block (32 | 1024)

    sc[t] = (t < RG) ? cnt_parts[t * D + d] : 0;

    const float2* __restrict__ pp = (const float2*)partials;
    float s1 = 0.f, s2 = 0.f;
#pragma unroll
    for (int r = 0; r < 16; ++r) {
      const int rg = ch * 16 + r;
      float2 v = pp[(size_t)rg * (D * F) + p];
      s1 += v.x;
      s2 += v.y;
    }

    sf[ch][i][0] = s1;
    sf[ch][i][1] = s2;
    __syncthreads();
    for (int s = 128; s > 0; s >>= 1) {
      if (t < s) sc[t] += sc[t + s];
      __syncthreads();
    }

    if (t < 32) {
      float r1 = 0.f, r2 = 0.f;
#pragma unroll
      for (int c = 0; c < 8; ++c) {
        r1 += sf[c][t][0];
        r2 += sf[c][t][1];
      }
      const int pw = b * 32 + t;
      const float c = (float)sc[0];
      const float cc = fmaxf(c, 1.f);
      const float mean = r1 / cc;
      const float var = r2 / cc - mean * mean;
      const float inv = rsqrtf(var + EPSV);
      float scv = gamma[pw] * inv;
      float shv = beta[pw] - mean * scv;
      if (c <= 1.f) {  // count==1: passthrough x; count==0: zero
        scv = (c == 1.f) ? 1.f : 0.f;
        shv = 0.f;
      }
      scale[pw] = scv;
      shift[pw] = shv;
    }
  }

  gg.sync();

  // ---------------- phase 3: apply ----------------
  {
    const int n0 = b * 64;  // 256 blocks x 64 rows = N
    for (int r = 0; r < 64; r += 8) {
      int dd[8];
#pragma unroll
      for (int j = 0; j < 8; ++j) dd[j] = y[n0 + r + j];  // uniform -> s_load
#pragma unroll
      for (int j = 0; j < 8; ++j) {
        const int n = n0 + r + j;
        const float4 v = ((const float4*)x)[(size_t)n * 256 + t];
        const float4 g = ((const float4*)scale)[dd[j] * 256 + t];
        const float4 bb = ((const float4*)shift)[dd[j] * 256 + t];
        float4 o;
        o.x = fmaf(v.x, g.x, bb.x);
        o.y = fmaf(v.y, g.y, bb.y);
        o.z = fmaf(v.z, g.z, bb.z);
        o.w = fmaf(v.w, g.w, bb.w);
        ((float4*)out)[(size_t)n * 256 + t] = o;
      }
    }
  }
}

extern "C" void kernel_launch(void* const* d_in, const int* in_sizes, int n_in,
                              void* d_out, int out_size, void* d_ws, size_t ws_size,
                              hipStream_t stream) {
  const float* x = (const float*)d_in[0];
  const int* y = (const int*)d_in[1];
  const float* gamma = (const float*)d_in[2];
  const float* beta = (const float*)d_in[3];
  float* out = (float*)d_out;

  // ws layout (floats):
  //   partials : RG*D*F*2 = 2,097,152 (8 MiB)
  //   cnt_parts: RG*D ints =    1,024
  //   scale    : D*F       =    8,192
  //   shift    : D*F       =    8,192
  float* partials = (float*)d_ws;
  int* cnt_parts = (int*)(partials + (size_t)RG * D * F * 2);
  float* scale = (float*)(cnt_parts + RG * D);
  float* shift = scale + D * F;

  void* args[] = {(void*)&x,   (void*)&y,         (void*)&gamma,
                  (void*)&beta, (void*)&out,      (void*)&partials,
                  (void*)&cnt_parts, (void*)&scale, (void*)&shift};
  hipLaunchCooperativeKernel((const void*)ds_bn_fused, dim3(GRID), dim3(256),
                             args, 0, stream);
}

// Round 6
// 146.020 us; speedup vs baseline: 1.4991x; 1.4991x over previous
//
#include <hip/hip_runtime.h>

// DSBatchNorm: per-domain batch stats + affine. N=16384 rows, F=1024 feats, D=8 domains.
// Three-kernel structure (R4-proven; cooperative fusion measured 3x WORSE — 1 block/CU
// + grid syncs made it latency-bound at 15% HBM BW).
// k1: RG=128 rowgroups (halves partials vs R4: 8 MiB round-trip instead of 16),
//     grid=256 (1 block/CU — k1 is HBM-bound with 8 loads in flight/thread).
// k2: single-kernel 128->1 reduction, 256 blocks, coalesced along rowgroup axis.
// k3: out = x*scale[y] + shift[y], 2048 blocks x 8 rows, branch-free (x read is L3-warm;
//     write-bound ~11us).

#define EPSV 1e-5f
constexpr int N = 16384;
constexpr int F = 1024;
constexpr int D = 8;
constexpr int RPB = 128;      // rows per rowgroup
constexpr int RG = N / RPB;   // 128 rowgroups

// ---------------- kernel 1: partial sums ----------------
// grid = RG*2 (2 column halves), block = 256. Each thread owns 2 consecutive
// floats (float2) of one half-row; acc[8] per-domain in registers.
// y[n] address is uniform (block/loop indices only) -> s_load + uniform branch.
__global__ __launch_bounds__(256) void k1_partials(
    const float* __restrict__ x, const int* __restrict__ y,
    float* __restrict__ partials, int* __restrict__ cnt_parts) {
  const int t = threadIdx.x;
  const int rg = blockIdx.x >> 1;
  const int h = blockIdx.x & 1;

  __shared__ int hist[D];
  if (t < D) hist[t] = 0;
  __syncthreads();
  if (h == 0 && t < RPB) atomicAdd(&hist[y[rg * RPB + t]], 1);
  __syncthreads();
  if (h == 0 && t < D) cnt_parts[rg * D + t] = hist[t];  // one writer per rg

  float2 a1[D], a2[D];
#pragma unroll
  for (int k = 0; k < D; ++k) {
    a1[k] = make_float2(0.f, 0.f);
    a2[k] = make_float2(0.f, 0.f);
  }

  const float2* __restrict__ x2 = (const float2*)x;
  const int col2 = h * 256 + t;  // float2 column index, 0..511
  const int row0 = rg * RPB;

#define ACC(K)                            \
  a1[K].x += v.x;                         \
  a1[K].y += v.y;                         \
  a2[K].x = fmaf(v.x, v.x, a2[K].x);      \
  a2[K].y = fmaf(v.y, v.y, a2[K].y);      \
  break;

  for (int r = 0; r < RPB; r += 8) {
    const int n = row0 + r;
    int dd[8];
    float2 vv[8];
#pragma unroll
    for (int j = 0; j < 8; ++j) dd[j] = y[n + j];        // uniform -> SGPR
#pragma unroll
    for (int j = 0; j < 8; ++j) vv[j] = x2[(size_t)(n + j) * 512 + col2];  // 8 in flight
#pragma unroll
    for (int j = 0; j < 8; ++j) {
      float2 v = vv[j];
      switch (dd[j]) {
        case 0: ACC(0)
        case 1: ACC(1)
        case 2: ACC(2)
        case 3: ACC(3)
        case 4: ACC(4)
        case 5: ACC(5)
        case 6: ACC(6)
        case 7: ACC(7)
      }
    }
  }
#undef ACC

  // partials as float2: pp[(rg*D + d)*1024 + f] = (s1, s2)
  float4* __restrict__ p4 = (float4*)partials;
#pragma unroll
  for (int k = 0; k < D; ++k) {
    float4 w = make_float4(a1[k].x, a2[k].x, a1[k].y, a2[k].y);
    p4[(rg * D + k) * 512 + h * 256 + t] = w;
  }
}

// ---------------- kernel 2: full stats reduction -> scale/shift ----------------
// grid = 256 blocks, block = 256. Block b owns 32 consecutive (d,f) pairs
// (p = b*32 + (t&31); d uniform per block). Thread t reduces rg-chunk (t>>5):
// 16 float2 loads, half-wave reads are 256B contiguous. LDS finishes 8 chunks.
__global__ __launch_bounds__(256) void k2_stats(
    const float* __restrict__ partials, const int* __restrict__ cnt_parts,
    const float* __restrict__ gamma, const float* __restrict__ beta,
    float* __restrict__ scale, float* __restrict__ shift) {
  const int t = threadIdx.x;
  const int i = t & 31;        // pair within block
  const int ch = t >> 5;       // rg-chunk, 0..7 (16 rowgroups each)
  const int p = blockIdx.x * 32 + i;  // (d,f) flat
  const int d = p >> 10;       // uniform per block (32 | 1024)

  // counts: RG per-rowgroup histogram entries for domain d, tree-reduced.
  __shared__ int sc[256];
  sc[t] = (t < RG) ? cnt_parts[t * D + d] : 0;

  const float2* __restrict__ pp = (const float2*)partials;
  float s1 = 0.f, s2 = 0.f;
#pragma unroll
  for (int r = 0; r < 16; ++r) {
    const int rg = ch * 16 + r;
    float2 v = pp[(size_t)rg * (D * F) + p];
    s1 += v.x;
    s2 += v.y;
  }

  __shared__ float sf[8][32][2];
  sf[ch][i][0] = s1;
  sf[ch][i][1] = s2;
  __syncthreads();
  for (int s = 128; s > 0; s >>= 1) {
    if (t < s) sc[t] += sc[t + s];
    __syncthreads();
  }

  if (t < 32) {
    float r1 = 0.f, r2 = 0.f;
#pragma unroll
    for (int c = 0; c < 8; ++c) {
      r1 += sf[c][t][0];
      r2 += sf[c][t][1];
    }
    const int pw = blockIdx.x * 32 + t;
    const float c = (float)sc[0];
    const float cc = fmaxf(c, 1.f);
    const float mean = r1 / cc;
    const float var = r2 / cc - mean * mean;
    const float inv = rsqrtf(var + EPSV);
    float scv = gamma[pw] * inv;
    float shv = beta[pw] - mean * scv;
    if (c <= 1.f) {  // count==1: passthrough x; count==0: zero output
      scv = (c == 1.f) ? 1.f : 0.f;
      shv = 0.f;
    }
    scale[pw] = scv;
    shift[pw] = shv;
  }
}

// ---------------- kernel 3: apply ----------------
// grid = N/8 = 2048 blocks, block = 256; 8 rows/block, one float4 per thread
// per row (256*4 = F). All 8 rows unrolled: 24 loads in flight per thread.
__global__ __launch_bounds__(256) void k3_apply(
    const float* __restrict__ x, const int* __restrict__ y,
    const float* __restrict__ scale, const float* __restrict__ shift,
    float* __restrict__ out) {
  const int t = threadIdx.x;
  const int n0 = blockIdx.x * 8;

  int dd[8];
#pragma unroll
  for (int j = 0; j < 8; ++j) dd[j] = y[n0 + j];  // uniform -> s_load

#pragma unroll
  for (int j = 0; j < 8; ++j) {
    const int n = n0 + j;
    const float4 v = ((const float4*)x)[(size_t)n * 256 + t];
    const float4 g = ((const float4*)scale)[dd[j] * 256 + t];
    const float4 b = ((const float4*)shift)[dd[j] * 256 + t];
    float4 o;
    o.x = fmaf(v.x, g.x, b.x);
    o.y = fmaf(v.y, g.y, b.y);
    o.z = fmaf(v.z, g.z, b.z);
    o.w = fmaf(v.w, g.w, b.w);
    ((float4*)out)[(size_t)n * 256 + t] = o;
  }
}

extern "C" void kernel_launch(void* const* d_in, const int* in_sizes, int n_in,
                              void* d_out, int out_size, void* d_ws, size_t ws_size,
                              hipStream_t stream) {
  const float* x = (const float*)d_in[0];
  const int* y = (const int*)d_in[1];
  const float* gamma = (const float*)d_in[2];
  const float* beta = (const float*)d_in[3];
  float* out = (float*)d_out;

  // ws layout (floats):
  //   partials : RG*D*F*2 = 2,097,152 (8 MiB)
  //   cnt_parts: RG*D ints =    1,024
  //   scale    : D*F       =    8,192
  //   shift    : D*F       =    8,192
  float* partials = (float*)d_ws;
  int* cnt_parts = (int*)(partials + (size_t)RG * D * F * 2);
  float* scale = (float*)(cnt_parts + RG * D);
  float* shift = scale + D * F;

  k1_partials<<<RG * 2, 256, 0, stream>>>(x, y, partials, cnt_parts);
  k2_stats<<<256, 256, 0, stream>>>(partials, cnt_parts, gamma, beta, scale, shift);
  k3_apply<<<N / 8, 256, 0, stream>>>(x, y, scale, shift, out);
}